// Round 4
// baseline (429.946 us; speedup 1.0000x reference)
//
#include <hip/hip_runtime.h>
#include <hip/hip_bf16.h>

// GraphSAGE fused gather + weighted-mean + Linear(256->128) + ReLU
// N=100000, K=16, D=128, V=1e6 rows (f32 table).
//
// Round 4: wave-level work stealing. Grid = 1024 persistent-ish blocks;
// each wave grabs 32-node tiles from a global atomic counter (zeroed by the
// prep kernel every call -> deterministic output). Removes the ragged
// 1.5-fill scheduling tail of the fixed 1563-block grid. Phase 1 (paired
// float4 row gathers) and phase 2 (bf16 MFMA vs pre-transposed W1T,
// XOR-swizzled LDS comb) unchanged from round 3.

#define NN 100000
#define KK 16
#define DD 128
#define MM 16          // nodes per 16-node tile (one MFMA N-tile)
#define WPB 4          // waves per block
#define GRAB 32        // nodes per atomic grab (2 tiles)
#define NGRABS (NN / GRAB)   // 3125

typedef __attribute__((ext_vector_type(8))) short short8;   // 8 x bf16
typedef __attribute__((ext_vector_type(4))) float f32x4;

// ---- prep: W1T[d][k] = bf16(W1[k][d]); also zero the work counter ----
__global__ __launch_bounds__(256)
void prep_w1t_kernel(const float* __restrict__ W1, __hip_bfloat16* __restrict__ W1T,
                     int* __restrict__ counter)
{
    const int tid = blockIdx.x * blockDim.x + threadIdx.x;  // 32768 threads
    if (tid == 0) *counter = 0;
    const int d = tid >> 8;      // 0..127
    const int k = tid & 255;     // 0..255
    W1T[d * 256 + k] = __float2bfloat16(W1[k * DD + d]);
}

static __device__ __forceinline__ unsigned pk_bf16(float a, float b) {
    __hip_bfloat162 t;
    t.x = __float2bfloat16(a);
    t.y = __float2bfloat16(b);
    return *reinterpret_cast<unsigned*>(&t);
}

__global__ __launch_bounds__(256, 4)
void graphsage_kernel(const int* __restrict__ video_nodes,
                      const int* __restrict__ neighbors,
                      const float* __restrict__ neigh_weights,
                      const float* __restrict__ emb,
                      const __hip_bfloat16* __restrict__ W1T,
                      const float* __restrict__ b1,
                      float* __restrict__ out,
                      int* __restrict__ counter)
{
    // per-wave comb slot: [MM nodes][256 k] bf16 = 8 KB; 4 waves -> 32 KB
    __shared__ __hip_bfloat16 comb[WPB][MM][2 * DD];

    const int lane = threadIdx.x & 63;
    const int wib  = __builtin_amdgcn_readfirstlane(threadIdx.x >> 6);

    char* const slot = (char*)&comb[wib][0][0];
    const char* const embB = (const char*)emb;

    const int half = lane >> 5;               // which node of a load pair
    const int c    = lane & 31;               // column group: floats 4c..4c+3
    const unsigned byte_c = 16u * (unsigned)c;

    for (;;) {
        // ---- steal a 32-node tile ----
        int grab = 0;
        if (lane == 0) grab = atomicAdd(counter, 1);
        grab = __shfl(grab, 0);
        if (grab >= NGRABS) break;            // wave-uniform exit; no barriers used

        int node0 = grab * GRAB;
        #pragma unroll 1
        for (int t16 = 0; t16 < GRAB / MM; ++t16, node0 += MM) {

            // ---- Phase 1: paired gathers + weighted mean -> bf16 LDS ----
            #pragma unroll 2
            for (int mp = 0; mp < MM / 2; ++mp) {
                const int n0 = node0 + 2 * mp;        // wave-uniform
                const int n1 = n0 + 1;

                const int s0i = video_nodes[n0];      // scalar
                const int s1i = video_nodes[n1];      // scalar
                const int sidx = half ? s1i : s0i;
                const float4 sv = *reinterpret_cast<const float4*>(
                    embB + ((((unsigned)sidx) << 9) + byte_c));

                f32x4 acc = {0.0f, 0.0f, 0.0f, 0.0f};
                float wsum = 0.0f;
                #pragma unroll
                for (int k = 0; k < KK; ++k) {
                    const int   i0 = neighbors[n0 * KK + k];        // scalar
                    const int   i1 = neighbors[n1 * KK + k];        // scalar
                    const float w0 = neigh_weights[n0 * KK + k];    // scalar
                    const float w1 = neigh_weights[n1 * KK + k];    // scalar
                    const int   rk = half ? i1 : i0;                // cndmask
                    const float wk = half ? w1 : w0;                // cndmask
                    wsum += wk;
                    const float4 e = *reinterpret_cast<const float4*>(
                        embB + ((((unsigned)rk) << 9) + byte_c));
                    acc[0] = fmaf(wk, e.x, acc[0]);
                    acc[1] = fmaf(wk, e.y, acc[1]);
                    acc[2] = fmaf(wk, e.z, acc[2]);
                    acc[3] = fmaf(wk, e.w, acc[3]);
                }
                const float inv = 1.0f / wsum;

                // element j of node's 256-wide comb row lives at byte
                // (node*512 + 2j) ^ ((node&7)<<4); this lane owns self
                // j=4c..4c+3 and neigh j=128+4c..128+4c+3 -> two 8 B writes.
                const int nodel = 2 * mp + half;
                const unsigned swz = (unsigned)((nodel & 7) << 4);
                const unsigned sb = ((unsigned)(nodel * 512) + 8u * c) ^ swz;
                const unsigned nb = ((unsigned)(nodel * 512 + 256) + 8u * c) ^ swz;

                uint2 sU, nU;
                sU.x = pk_bf16(sv.x, sv.y);
                sU.y = pk_bf16(sv.z, sv.w);
                nU.x = pk_bf16(acc[0] * inv, acc[1] * inv);
                nU.y = pk_bf16(acc[2] * inv, acc[3] * inv);
                *reinterpret_cast<uint2*>(slot + sb) = sU;
                *reinterpret_cast<uint2*>(slot + nb) = nU;
            }
            // wave-private slot: same-wave ds ordering via lgkmcnt.

            // ---- Phase 2: D[d][node] = sum_k W1T[d][k]*comb[node][k] ----
            const int nodeB  = lane & 15;
            const int kchunk = lane >> 4;
            const unsigned swzB = (unsigned)((nodeB & 7) << 4);

            short8 bfrag[8];
            #pragma unroll
            for (int kt = 0; kt < 8; ++kt) {
                const unsigned byte =
                    ((unsigned)(nodeB * 512 + kt * 64 + kchunk * 16)) ^ swzB;
                bfrag[kt] = *reinterpret_cast<const short8*>(slot + byte);
            }

            const int drow = lane & 15;
            #pragma unroll
            for (int dt = 0; dt < 8; ++dt) {
                const int d = dt * 16 + drow;
                f32x4 acc = {0.0f, 0.0f, 0.0f, 0.0f};
                #pragma unroll
                for (int kt = 0; kt < 8; ++kt) {
                    const short8 afrag = *reinterpret_cast<const short8*>(
                        &W1T[d * 256 + kt * 32 + kchunk * 8]);
                    acc = __builtin_amdgcn_mfma_f32_16x16x32_bf16(
                        afrag, bfrag[kt], acc, 0, 0, 0);
                }
                // D: col = lane&15 = node, row = kchunk*4 + reg
                const int node = node0 + (lane & 15);
                const int d0   = dt * 16 + kchunk * 4;
                const float4 bias = *reinterpret_cast<const float4*>(&b1[d0]);
                float4 r;
                r.x = fmaxf(acc[0] + bias.x, 0.0f);
                r.y = fmaxf(acc[1] + bias.y, 0.0f);
                r.z = fmaxf(acc[2] + bias.z, 0.0f);
                r.w = fmaxf(acc[3] + bias.w, 0.0f);
                *reinterpret_cast<float4*>(&out[(size_t)node * DD + d0]) = r;
            }
        }
    }
}

extern "C" void kernel_launch(void* const* d_in, const int* in_sizes, int n_in,
                              void* d_out, int out_size, void* d_ws, size_t ws_size,
                              hipStream_t stream) {
    const int*   video_nodes   = (const int*)d_in[0];
    const int*   neighbors     = (const int*)d_in[1];
    const float* neigh_weights = (const float*)d_in[2];
    const float* emb           = (const float*)d_in[3];
    const float* W1            = (const float*)d_in[4];
    const float* b1            = (const float*)d_in[5];
    float*       out           = (float*)d_out;

    __hip_bfloat16* W1T = (__hip_bfloat16*)d_ws;                 // 64 KB
    int* counter = (int*)((char*)d_ws + (128 * 256 * 2));        // after W1T

    prep_w1t_kernel<<<DD * 256 / 256, 256, 0, stream>>>(W1, W1T, counter);

    // 4 blocks/CU resident; work stealing balances the rest.
    const int grid = 1024;
    graphsage_kernel<<<grid, 256, 0, stream>>>(
        video_nodes, neighbors, neigh_weights, emb, W1T, b1, out, counter);
}

// Round 5
// 167.777 us; speedup vs baseline: 2.5626x; 2.5626x over previous
//
#include <hip/hip_runtime.h>
#include <hip/hip_bf16.h>

// GraphSAGE fused gather + weighted-mean + Linear(256->128) + ReLU
// N=100000, K=16, D=128, V=1e6 rows (f32 table).
//
// Round 5: round-3 structure (fixed grid 1563x256, 16 nodes/wave, paired
// float4 row gathers, bf16 MFMA vs pre-transposed W1T) + WRITE-side fix.
// Round-4 counters showed WRITE_SIZE = 408 MB = 8x the 51 MB output: the
// old epilogue's 16B/lane scattered stores cost a ~128B HBM granule each.
// New epilogue: stage bias+ReLU output in the (dead) comb LDS slot with the
// same XOR swizzle, then store linearly -- lanes 0-31 cover one full 512 B
// row, lanes 32-63 the next. Full-granule writes, same shape as the gathers.

#define NN 100000
#define KK 16
#define DD 128
#define MM 16          // nodes per wave
#define WPB 4          // waves per block

typedef __attribute__((ext_vector_type(8))) short short8;   // 8 x bf16
typedef __attribute__((ext_vector_type(4))) float f32x4;

// ---- prep: W1T[d][k] = bf16(W1[k][d]) ----
__global__ __launch_bounds__(256)
void prep_w1t_kernel(const float* __restrict__ W1, __hip_bfloat16* __restrict__ W1T)
{
    const int tid = blockIdx.x * blockDim.x + threadIdx.x;  // 32768 threads
    const int d = tid >> 8;      // 0..127
    const int k = tid & 255;     // 0..255
    W1T[d * 256 + k] = __float2bfloat16(W1[k * DD + d]);
}

static __device__ __forceinline__ unsigned pk_bf16(float a, float b) {
    __hip_bfloat162 t;
    t.x = __float2bfloat16(a);
    t.y = __float2bfloat16(b);
    return *reinterpret_cast<unsigned*>(&t);
}

__global__ __launch_bounds__(256, 4)
void graphsage_kernel(const int* __restrict__ video_nodes,
                      const int* __restrict__ neighbors,
                      const float* __restrict__ neigh_weights,
                      const float* __restrict__ emb,
                      const __hip_bfloat16* __restrict__ W1T,
                      const float* __restrict__ b1,
                      float* __restrict__ out)
{
    // per-wave slot: phase 1/2: [MM nodes][256 k] bf16 = 8 KB;
    // epilogue reuses it as [MM nodes][128 d] f32 (same 512 B/node geometry).
    __shared__ __hip_bfloat16 comb[WPB][MM][2 * DD];

    const int lane = threadIdx.x & 63;
    const int wib  = __builtin_amdgcn_readfirstlane(threadIdx.x >> 6);
    const int node0 = (blockIdx.x * WPB + wib) * MM;
    if (node0 >= NN) return;   // 6250 full waves; trailing waves exit whole

    char* const slot = (char*)&comb[wib][0][0];
    const char* const embB = (const char*)emb;
    char* const outB = (char*)out;

    const int half = lane >> 5;               // which node of the pair
    const int c    = lane & 31;               // column group: floats 4c..4c+3
    const unsigned byte_c = 16u * (unsigned)c;

    // ---- Phase 1: paired gathers + weighted mean, pack bf16 into LDS ----
    #pragma unroll 2
    for (int mp = 0; mp < MM / 2; ++mp) {
        const int n0 = node0 + 2 * mp;        // wave-uniform
        const int n1 = n0 + 1;

        const int s0i = video_nodes[n0];      // scalar
        const int s1i = video_nodes[n1];      // scalar
        const int sidx = half ? s1i : s0i;
        const float4 sv = *reinterpret_cast<const float4*>(
            embB + ((((unsigned)sidx) << 9) + byte_c));

        f32x4 acc = {0.0f, 0.0f, 0.0f, 0.0f};
        float wsum = 0.0f;
        #pragma unroll
        for (int k = 0; k < KK; ++k) {
            const int   i0 = neighbors[n0 * KK + k];        // scalar
            const int   i1 = neighbors[n1 * KK + k];        // scalar
            const float w0 = neigh_weights[n0 * KK + k];    // scalar
            const float w1 = neigh_weights[n1 * KK + k];    // scalar
            const int   rk = half ? i1 : i0;                // cndmask
            const float wk = half ? w1 : w0;                // cndmask
            wsum += wk;
            const float4 e = *reinterpret_cast<const float4*>(
                embB + ((((unsigned)rk) << 9) + byte_c));   // saddr + 32b voff
            acc[0] = fmaf(wk, e.x, acc[0]);
            acc[1] = fmaf(wk, e.y, acc[1]);
            acc[2] = fmaf(wk, e.z, acc[2]);
            acc[3] = fmaf(wk, e.w, acc[3]);
        }
        const float inv = 1.0f / wsum;

        // element j of node's 256-wide comb row lives at byte
        // (node*512 + 2j) ^ ((node&7)<<4); this lane owns self j=4c..4c+3
        // and neigh j=128+4c..128+4c+3 -> two 8 B writes.
        const int nodel = 2 * mp + half;
        const unsigned swz = (unsigned)((nodel & 7) << 4);
        const unsigned sb = ((unsigned)(nodel * 512) + 8u * c) ^ swz;
        const unsigned nb = ((unsigned)(nodel * 512 + 256) + 8u * c) ^ swz;

        uint2 sU, nU;
        sU.x = pk_bf16(sv.x, sv.y);
        sU.y = pk_bf16(sv.z, sv.w);
        nU.x = pk_bf16(acc[0] * inv, acc[1] * inv);
        nU.y = pk_bf16(acc[2] * inv, acc[3] * inv);
        *reinterpret_cast<uint2*>(slot + sb) = sU;
        *reinterpret_cast<uint2*>(slot + nb) = nU;
    }
    // wave-private slot: same-wave ds ordering via lgkmcnt + data deps.

    // ---- Phase 2: MFMA.  D[d][node] = sum_k W1T[d][k] * comb[node][k] ----
    const int nodeB  = lane & 15;    // B col / D col / output node
    const int kchunk = lane >> 4;    // 0..3
    const unsigned swzB = (unsigned)((nodeB & 7) << 4);

    short8 bfrag[8];
    #pragma unroll
    for (int kt = 0; kt < 8; ++kt) {
        const unsigned byte =
            ((unsigned)(nodeB * 512 + kt * 64 + kchunk * 16)) ^ swzB;
        bfrag[kt] = *reinterpret_cast<const short8*>(slot + byte);
    }

    const int drow = lane & 15;      // A row within d-tile
    #pragma unroll
    for (int dt = 0; dt < 8; ++dt) {
        const int d = dt * 16 + drow;
        f32x4 acc = {0.0f, 0.0f, 0.0f, 0.0f};
        #pragma unroll
        for (int kt = 0; kt < 8; ++kt) {
            const short8 afrag = *reinterpret_cast<const short8*>(
                &W1T[d * 256 + kt * 32 + kchunk * 8]);
            acc = __builtin_amdgcn_mfma_f32_16x16x32_bf16(afrag, bfrag[kt], acc,
                                                          0, 0, 0);
        }
        // D: col = lane&15 = node, row = kchunk*4 + reg = d within tile.
        // Stage bias+ReLU result in the slot (f32, [node][128d], swizzled).
        // acc depends on ALL bfrag reads -> these ds_writes cannot be
        // reordered before the bfrag ds_reads.
        const int d0 = dt * 16 + kchunk * 4;
        const float4 bias = *reinterpret_cast<const float4*>(&b1[d0]);
        f32x4 r;
        r[0] = fmaxf(acc[0] + bias.x, 0.0f);
        r[1] = fmaxf(acc[1] + bias.y, 0.0f);
        r[2] = fmaxf(acc[2] + bias.z, 0.0f);
        r[3] = fmaxf(acc[3] + bias.w, 0.0f);
        const unsigned tb = ((unsigned)(nodeB * 512 + d0 * 4)) ^ swzB;
        *reinterpret_cast<f32x4*>(slot + tb) = r;
    }

    // ---- Epilogue: linear LDS read -> full-row contiguous global stores.
    // Instruction i: lanes 0-31 cover row (2i) bytes 0..511, lanes 32-63
    // row (2i+1). 8 instructions = 16 rows x 512 B, all full-granule.
    #pragma unroll
    for (int i = 0; i < 8; ++i) {
        const unsigned o     = (unsigned)i * 1024u + (unsigned)lane * 16u;
        const unsigned nodel = o >> 9;
        const unsigned rb    = o & 511u;
        const unsigned lb    = nodel * 512u + (rb ^ ((nodel & 7u) << 4));
        const float4 v = *reinterpret_cast<const float4*>(slot + lb);
        *reinterpret_cast<float4*>(
            outB + ((size_t)(node0 + nodel) << 9) + rb) = v;
    }
}

extern "C" void kernel_launch(void* const* d_in, const int* in_sizes, int n_in,
                              void* d_out, int out_size, void* d_ws, size_t ws_size,
                              hipStream_t stream) {
    const int*   video_nodes   = (const int*)d_in[0];
    const int*   neighbors     = (const int*)d_in[1];
    const float* neigh_weights = (const float*)d_in[2];
    const float* emb           = (const float*)d_in[3];
    const float* W1            = (const float*)d_in[4];
    const float* b1            = (const float*)d_in[5];
    float*       out           = (float*)d_out;

    __hip_bfloat16* W1T = (__hip_bfloat16*)d_ws;   // 64 KB

    prep_w1t_kernel<<<DD * 256 / 256, 256, 0, stream>>>(W1, W1T);

    const int nodes_per_block = WPB * MM;                          // 64
    const int grid = (NN + nodes_per_block - 1) / nodes_per_block; // 1563
    graphsage_kernel<<<grid, 256, 0, stream>>>(
        video_nodes, neighbors, neigh_weights, emb, W1T, b1, out);
}